// Round 5
// baseline (115.774 us; speedup 1.0000x reference)
//
#include <hip/hip_runtime.h>
#include <math.h>

// Problem constants: FX=FY=48, CX=48, CY=36, H=72, W=96, sigma2=1
#define NPIX 6912
#define LOG2E 1.4426950408889634f

typedef __fp16 v8h __attribute__((ext_vector_type(8)));
typedef float  v4f __attribute__((ext_vector_type(4)));

// ws byte offsets (all 32B-aligned)
#define OFF_ROWFEAT 0         // [N][16] f16  f1n features (a-frag source)
#define OFF_ROWGEO  221184    // [N][16] f16  [ph x3, ph x3, pl x3, pl x3, 0 x4], p~=log2e*p1 hi/lo split
#define OFF_W       442368    // [N] f32      w = -log2e*|p1|^2/2
#define OFF_COLFEAT 470016    // [N][16] f16  f2n features (b-frag source)
#define OFF_COLB1   691200    // [N][16] f16  [th x3, tl x3, th x3, tl x3, 0 x4], t hi/lo split
#define OFF_COLB2   912384    // [N][16] f16  [dt x3, 0 x3, dt x3, 0 x7], dt = q - t (f16)
#define OFF_COLGEO  1133568   // [N][2] f32   {cA = -log2e*|t|^2/2,  dc = log2e*(|t|^2-|q|^2)/2}
// total ~1.14 MB

__device__ __forceinline__ float fast_exp2(float x) { return __builtin_amdgcn_exp2f(x); }

__device__ __forceinline__ float block_reduce_256(float v, float* smem4) {
    __syncthreads();
    #pragma unroll
    for (int o = 32; o > 0; o >>= 1) v += __shfl_down(v, o, 64);
    int lane = threadIdx.x & 63;
    int w = threadIdx.x >> 6;
    if (lane == 0) smem4[w] = v;
    __syncthreads();
    float r = 0.0f;
    if (threadIdx.x == 0) r = smem4[0] + smem4[1] + smem4[2] + smem4[3];
    return r;
}

__global__ __launch_bounds__(256)
void preproc_kernel(const float* __restrict__ f1, const float* __restrict__ f2,
                    const float* __restrict__ d1, const float* __restrict__ d2,
                    const float* __restrict__ pose, const float* __restrict__ pnz,
                    char* __restrict__ wsb, float* __restrict__ out) {
    __shared__ float smem4[4];
    const int i = blockIdx.x * 256 + threadIdx.x;

    __fp16* rowfeat = (__fp16*)(wsb + OFF_ROWFEAT);
    __fp16* rowgeo  = (__fp16*)(wsb + OFF_ROWGEO);
    float*  wArr    = (float*)(wsb + OFF_W);
    __fp16* colfeat = (__fp16*)(wsb + OFF_COLFEAT);
    __fp16* colB1   = (__fp16*)(wsb + OFF_COLB1);
    __fp16* colB2   = (__fp16*)(wsb + OFF_COLB2);
    float*  colgeo  = (float*)(wsb + OFF_COLGEO);

    // pose rows 0..2 (uniform -> scalar)
    float P[12];
    #pragma unroll
    for (int k = 0; k < 12; k++) P[k] = pose[k];
    float Q[12];
    #pragma unroll
    for (int r = 0; r < 3; r++) {
        #pragma unroll
        for (int c = 0; c < 4; c++) {
            float s = 0.0f;
            #pragma unroll
            for (int k = 0; k < 4; k++) s = fmaf(pose[r * 4 + k], pnz[k * 4 + c], s);
            Q[r * 4 + c] = s;
        }
    }

    const float inv48 = 1.0f / 48.0f;
    const int u = i % 96;
    const int v = i / 96;
    const float y1 = fmaf((float)u, inv48, -1.0f);
    const float y2 = fmaf((float)v, inv48, -0.75f);

    // ---- row side: p1 = yz1 * depth1 ----
    const float dep1 = d1[i];
    const float px = dep1, py = y1 * dep1, pz = y2 * dep1;
    const float n1 = px * px + py * py + pz * pz;
    wArr[i] = -0.5f * LOG2E * n1;

    // p~ = log2e * p1, hi/lo f16 split
    const float ptx = LOG2E * px, pty = LOG2E * py, ptz = LOG2E * pz;
    const __fp16 phx = (__fp16)ptx, phy = (__fp16)pty, phz = (__fp16)ptz;
    const __fp16 plx = (__fp16)(ptx - (float)phx);
    const __fp16 ply = (__fp16)(pty - (float)phy);
    const __fp16 plz = (__fp16)(ptz - (float)phz);
    {
        __fp16 rg[16] = {phx, phy, phz, phx, phy, phz,
                         plx, ply, plz, plx, ply, plz,
                         (__fp16)0, (__fp16)0, (__fp16)0, (__fp16)0};
        *(v8h*)(rowgeo + (size_t)i * 16)     = *(v8h*)(rg);
        *(v8h*)(rowgeo + (size_t)i * 16 + 8) = *(v8h*)(rg + 8);
    }

    // ---- col side: p2 under both poses ----
    const float dep2 = d2[i];
    const float a = dep2, b = y1 * dep2, g = y2 * dep2;
    const float t0 = P[0] * a + P[1] * b + P[2]  * g + P[3];
    const float t1 = P[4] * a + P[5] * b + P[6]  * g + P[7];
    const float t2 = P[8] * a + P[9] * b + P[10] * g + P[11];
    const float q0 = Q[0] * a + Q[1] * b + Q[2]  * g + Q[3];
    const float q1 = Q[4] * a + Q[5] * b + Q[6]  * g + Q[7];
    const float q2 = Q[8] * a + Q[9] * b + Q[10] * g + Q[11];
    const float nt = t0 * t0 + t1 * t1 + t2 * t2;
    const float nq = q0 * q0 + q1 * q1 + q2 * q2;
    colgeo[(size_t)i * 2 + 0] = -0.5f * LOG2E * nt;               // cA
    colgeo[(size_t)i * 2 + 1] = 0.5f * LOG2E * (nt - nq);         // dc (a2-a1 col const)

    // t hi/lo split
    const __fp16 thx = (__fp16)t0, thy = (__fp16)t1, thz = (__fp16)t2;
    const __fp16 tlx = (__fp16)(t0 - (float)thx);
    const __fp16 tly = (__fp16)(t1 - (float)thy);
    const __fp16 tlz = (__fp16)(t2 - (float)thz);
    {
        __fp16 b1a[16] = {thx, thy, thz, tlx, tly, tlz,
                          thx, thy, thz, tlx, tly, tlz,
                          (__fp16)0, (__fp16)0, (__fp16)0, (__fp16)0};
        *(v8h*)(colB1 + (size_t)i * 16)     = *(v8h*)(b1a);
        *(v8h*)(colB1 + (size_t)i * 16 + 8) = *(v8h*)(b1a + 8);
    }
    // dt = q - t (small; single f16 suffices)
    const __fp16 dtx = (__fp16)(q0 - t0), dty = (__fp16)(q1 - t1), dtz = (__fp16)(q2 - t2);
    {
        __fp16 b2a[16] = {dtx, dty, dtz, (__fp16)0, (__fp16)0, (__fp16)0,
                          dtx, dty, dtz, (__fp16)0, (__fp16)0, (__fp16)0,
                          (__fp16)0, (__fp16)0, (__fp16)0, (__fp16)0};
        *(v8h*)(colB2 + (size_t)i * 16)     = *(v8h*)(b2a);
        *(v8h*)(colB2 + (size_t)i * 16 + 8) = *(v8h*)(b2a + 8);
    }

    // ---- features: normalize, f16 ----
    float s1 = 0.0f, s2 = 0.0f;
    float v1[16], v2[16];
    #pragma unroll
    for (int cc = 0; cc < 16; cc++) {
        v1[cc] = f1[cc * NPIX + i];
        v2[cc] = f2[cc * NPIX + i];
        s1 = fmaf(v1[cc], v1[cc], s1);
        s2 = fmaf(v2[cc], v2[cc], s2);
    }
    const float nrm1 = sqrtf(s1), nrm2 = sqrtf(s2);
    const float r1 = 1.0f / (nrm1 + 1e-8f), r2 = 1.0f / (nrm2 + 1e-8f);
    {
        __fp16 rf[16], cf[16];
        #pragma unroll
        for (int cc = 0; cc < 16; cc++) {
            rf[cc] = (__fp16)(v1[cc] * r1);
            cf[cc] = (__fp16)(v2[cc] * r2);
        }
        *(v8h*)(rowfeat + (size_t)i * 16)     = *(v8h*)(rf);
        *(v8h*)(rowfeat + (size_t)i * 16 + 8) = *(v8h*)(rf + 8);
        *(v8h*)(colfeat + (size_t)i * 16)     = *(v8h*)(cf);
        *(v8h*)(colfeat + (size_t)i * 16 + 8) = *(v8h*)(cf + 8);
    }

    float tot = block_reduce_256(nrm1 + nrm2, smem4);
    if (threadIdx.x == 0) atomicAdd(out + 2, 100.0f * tot);
}

// Pair kernel: block = 4 waves, each wave owns 32 rows (2 MFMA row-strips),
// sweeps 16 col-tiles of 16 cols. Grid (27, 54): block covers 128 rows x 256 cols.
// Per 16x16 tile: 3 MFMAs (dot, P=log2e*p.t, D=log2e*p.(q-t)), then per-lane
// fp32 epilogue: e1 = 2^(P + w_m + cA_n); e2 = e1 * 2^(D + dc_n);
// acc += (e1 - e2) * dot.   C/D map: row=(l>>4)*4+i, col=l&15 (m89-verified).
__global__ __launch_bounds__(256)
void pair_kernel(const char* __restrict__ wsb, float* __restrict__ out) {
    __shared__ float smem4[4];
    const __fp16* rowfeat = (const __fp16*)(wsb + OFF_ROWFEAT);
    const __fp16* rowgeo  = (const __fp16*)(wsb + OFF_ROWGEO);
    const float*  wArr    = (const float*)(wsb + OFF_W);
    const __fp16* colfeat = (const __fp16*)(wsb + OFF_COLFEAT);
    const __fp16* colB1   = (const __fp16*)(wsb + OFF_COLB1);
    const __fp16* colB2   = (const __fp16*)(wsb + OFF_COLB2);
    const float*  colgeo  = (const float*)(wsb + OFF_COLGEO);

    const int t    = threadIdx.x;
    const int w    = t >> 6;
    const int l    = t & 63;
    const int half = l >> 4;        // k-group selector
    const int nid  = l & 15;        // free-index (row for A, col for B/D)
    const bool lo32 = (half < 2);   // k>=16 slots are zero

    const int rbase = blockIdx.y * 128 + w * 32;

    // A-fragments + w vector: loaded once, live across the whole col sweep
    v8h afeat[2], ageo[2];
    v4f wv[2];
    #pragma unroll
    for (int s = 0; s < 2; s++) {
        const int rs = rbase + s * 16;
        v8h za = {}, zg = {};
        if (lo32) {
            za = *(const v8h*)(rowfeat + (size_t)(rs + nid) * 16 + half * 8);
            zg = *(const v8h*)(rowgeo  + (size_t)(rs + nid) * 16 + half * 8);
        }
        afeat[s] = za;
        ageo[s]  = zg;
        wv[s] = *(const v4f*)(wArr + rs + half * 4);   // w for C-rows half*4+{0..3}
    }

    const int cbase = blockIdx.x * 256;
    float acc = 0.0f;

    #pragma unroll 2
    for (int ct = 0; ct < 16; ct++) {
        const int n = cbase + ct * 16 + nid;
        v8h bfeat = {}, b1 = {}, b2 = {};
        if (lo32) {
            bfeat = *(const v8h*)(colfeat + (size_t)n * 16 + half * 8);
            b1    = *(const v8h*)(colB1   + (size_t)n * 16 + half * 8);
            b2    = *(const v8h*)(colB2   + (size_t)n * 16 + half * 8);
        }
        const float cAn = colgeo[(size_t)n * 2 + 0];
        const float dcn = colgeo[(size_t)n * 2 + 1];

        #pragma unroll
        for (int s = 0; s < 2; s++) {
            v4f z = {0.0f, 0.0f, 0.0f, 0.0f};
            v4f dotv = __builtin_amdgcn_mfma_f32_16x16x32_f16(afeat[s], bfeat, z, 0, 0, 0);
            v4f pv   = __builtin_amdgcn_mfma_f32_16x16x32_f16(ageo[s],  b1,    z, 0, 0, 0);
            v4f dv   = __builtin_amdgcn_mfma_f32_16x16x32_f16(ageo[s],  b2,    z, 0, 0, 0);
            #pragma unroll
            for (int i = 0; i < 4; i++) {
                const float a1 = pv[i] + wv[s][i] + cAn;     // log2 exponent of e1
                const float e1 = fast_exp2(a1);
                const float gg = dv[i] + dcn;                // delta = a2 - a1
                const float eg = fast_exp2(gg);
                acc = fmaf(e1 * (1.0f - eg), dotv[i], acc);  // (e1-e2)*dot
            }
        }
    }

    float tot = block_reduce_256(acc, smem4);
    if (t == 0) {
        const float vc = -tot * (1.0f / (float)NPIX);
        atomicAdd(out + 0, vc);   // final_loss
        atomicAdd(out + 1, vc);   // inner_neg
    }
}

extern "C" void kernel_launch(void* const* d_in, const int* in_sizes, int n_in,
                              void* d_out, int out_size, void* d_ws, size_t ws_size,
                              hipStream_t stream) {
    const float* feature1 = (const float*)d_in[0];
    const float* feature2 = (const float*)d_in[1];
    const float* depth1   = (const float*)d_in[2];
    const float* depth2   = (const float*)d_in[3];
    const float* pose1_2  = (const float*)d_in[4];
    const float* posenz   = (const float*)d_in[5];
    float* out = (float*)d_out;
    char*  wsb = (char*)d_ws;

    (void)hipMemsetAsync(d_out, 0, (size_t)out_size * sizeof(float), stream);

    preproc_kernel<<<27, 256, 0, stream>>>(feature1, feature2, depth1, depth2,
                                           pose1_2, posenz, wsb, out);
    dim3 grid(27, 54);
    pair_kernel<<<grid, 256, 0, stream>>>(wsb, out);
}